// Round 1
// baseline (1750.476 us; speedup 1.0000x reference)
//
#include <hip/hip_runtime.h>
#include <stdint.h>
#include <stddef.h>

#define D0 4096
#define D1 1024
#define NOUT 1000
#define NB 64

// ---------------------------------------------------------------------------
// Spike pattern for uniform spike coding, N in [0,32] -> 32-bit cycle mask.
// Matches jnp: spacing = 32.f/N (fp32), spike at c iff fmod(c, spacing) < 1.
// floor(c/spacing) < N is always true for 0<N<32 (margin >= N/32 >> fp eps).
// ---------------------------------------------------------------------------
__device__ __forceinline__ uint32_t spike_pattern(int N) {
  if (N <= 0) return 0u;
  if (N >= 32) return 0xFFFFFFFFu;
  float spacing = 32.0f / (float)N;
  uint32_t m = 0;
  for (int c = 0; c < 32; ++c) {
    if (fmodf((float)c, spacing) < 1.0f) m |= (1u << c);
  }
  return m;
}

// ---------------------------------------------------------------------------
// Transpose w0 (4096x4096) -> w0T[j][o]
// ---------------------------------------------------------------------------
__global__ void transpose_w0_k(const float* __restrict__ w, float* __restrict__ wt) {
  __shared__ float tile[32][33];
  int j0 = blockIdx.x * 32;
  int o0 = blockIdx.y * 32;
  int tx = threadIdx.x, ty = threadIdx.y; // 32 x 8
  for (int r = ty; r < 32; r += 8)
    tile[r][tx] = w[(size_t)(o0 + r) * D0 + j0 + tx];
  __syncthreads();
  for (int r = ty; r < 32; r += 8)
    wt[(size_t)(j0 + r) * D0 + o0 + tx] = tile[tx][r];
}

// Transpose w2 (1000x1024) -> w2T[j][o], o padded to 1024 with zeros.
__global__ void transpose_w2_k(const float* __restrict__ w, float* __restrict__ wt) {
  __shared__ float tile[32][33];
  int j0 = blockIdx.x * 32;
  int o0 = blockIdx.y * 32;
  int tx = threadIdx.x, ty = threadIdx.y;
  for (int r = ty; r < 32; r += 8) {
    int o = o0 + r;
    tile[r][tx] = (o < NOUT) ? w[(size_t)o * D1 + j0 + tx] : 0.0f;
  }
  __syncthreads();
  for (int r = ty; r < 32; r += 8)
    wt[(size_t)(j0 + r) * D1 + o0 + tx] = tile[tx][r];
}

// ---------------------------------------------------------------------------
// N0(b,d) = round_half_even(x * 32)   (matches jnp.round in fp32)
// ---------------------------------------------------------------------------
__global__ void compute_N0_k(const float* __restrict__ x, int* __restrict__ N0) {
  int i = blockIdx.x * 256 + threadIdx.x;
  N0[i] = (int)rintf(x[i] * 32.0f);
}

// ---------------------------------------------------------------------------
// Per-batch counting sort of D inputs by key = Nsrc[b][idx[j]] (33 keys).
// perm[b][pos] = (key << 16) | j, sorted ascending by key.
// Order within a key is non-deterministic (atomics) — only perturbs fp64
// bucket-sum rounding at ~1e-16, irrelevant vs ~1e-7 threshold gaps.
// ---------------------------------------------------------------------------
template <int D>
__global__ void prep_sort_k(const int* __restrict__ Nsrc, const int* __restrict__ idx,
                            uint32_t* __restrict__ perm) {
  __shared__ int keys[D];
  __shared__ int hist[33];
  __shared__ int base[33];
  int b = blockIdx.x;
  int tid = threadIdx.x;
  if (tid < 33) hist[tid] = 0;
  __syncthreads();
  for (int j = tid; j < D; j += 256) {
    int k = Nsrc[b * D + idx[j]];
    keys[j] = k;
    atomicAdd(&hist[k], 1);
  }
  __syncthreads();
  if (tid == 0) {
    int s = 0;
    for (int k = 0; k < 33; ++k) { base[k] = s; s += hist[k]; }
  }
  __syncthreads();
  for (int j = tid; j < D; j += 256) {
    int k = keys[j];
    int pos = atomicAdd(&base[k], 1);
    perm[b * D + pos] = ((uint32_t)k << 16) | (uint32_t)j;
  }
}

// ---------------------------------------------------------------------------
// LIF core via bucket decomposition, fp64-exact.
// Thread = one output neuron o for batch b. Stream the key-sorted perm,
// accumulating fp64 bucket sums of wt[p][o]; on key change, scatter the
// bucket sum into contrib[t] per the key's spike pattern. Then run the
// 32-step membrane scan (threshold-subtract reset) and emit the spike count.
// ---------------------------------------------------------------------------
template <int D, int OSTRIDE>
__launch_bounds__(256, 2)
__global__ void lif_core_k(const float* __restrict__ wt, const uint32_t* __restrict__ perm,
                           const float* __restrict__ thr_p, int* __restrict__ cnt_out) {
  __shared__ uint32_t pat[33];
  __shared__ uint32_t pbuf[256];
  int tid = threadIdx.x;
  int o = blockIdx.x * 256 + tid;
  int b = blockIdx.y;
  if (tid < 33) pat[tid] = spike_pattern(tid);
  __syncthreads();

  double contrib[32];
#pragma unroll
  for (int t = 0; t < 32; ++t) contrib[t] = 0.0;
  double acc = 0.0;
  uint32_t curkey = 0;
  const uint32_t* permb = perm + (size_t)b * D;

  for (int chunk = 0; chunk < D; chunk += 256) {
    __syncthreads();
    pbuf[tid] = permb[chunk + tid];
    __syncthreads();
    for (int ii = 0; ii < 256; ++ii) {
      uint32_t pk = pbuf[ii];
      uint32_t key = pk >> 16;
      if (key != curkey) {  // wave-uniform branch (same pk for all lanes)
        uint32_t m = pat[curkey];
#pragma unroll
        for (int t = 0; t < 32; ++t)
          contrib[t] += ((m >> t) & 1u) ? acc : 0.0;
        acc = 0.0;
        curkey = key;
      }
      acc += (double)wt[(size_t)(pk & 0xFFFFu) * OSTRIDE + o];
    }
  }
  {
    uint32_t m = pat[curkey];
#pragma unroll
    for (int t = 0; t < 32; ++t)
      contrib[t] += ((m >> t) & 1u) ? acc : 0.0;
  }

  double th = (double)thr_p[0];
  double memb = 0.0;
  int cnt = 0;
#pragma unroll
  for (int t = 0; t < 32; ++t) {
    memb += contrib[t];
    if (memb > th) { memb -= th; ++cnt; }  // strict: threshold < memb
  }
  cnt_out[(size_t)b * OSTRIDE + o] = cnt;
}

// ---------------------------------------------------------------------------
// avg_pool2d on exact spike counts + re-encode: N1 = round_half_even(count4/4)
// rates are exact multiples of 1/128; clip is a no-op (count4 <= 128).
// ---------------------------------------------------------------------------
__global__ void pool_encode_k(const int* __restrict__ k0, const int* __restrict__ idx1,
                              int* __restrict__ N1) {
  int i = blockIdx.x * 256 + threadIdx.x;  // 64*1024
  int b = i >> 10;
  int q2 = i & 1023;
  int c = q2 >> 4;
  int h2 = (q2 >> 2) & 3;
  int w2 = q2 & 3;
  int cnt = 0;
#pragma unroll
  for (int dh = 0; dh < 2; ++dh)
#pragma unroll
    for (int dw = 0; dw < 2; ++dw) {
      int q = c * 64 + (2 * h2 + dh) * 8 + (2 * w2 + dw);
      cnt += k0[b * D0 + idx1[q]];
    }
  N1[i] = (int)rintf((float)cnt * 0.25f);
}

__global__ void write_out_k(const int* __restrict__ cnt2, const int* __restrict__ idx_out,
                            float* __restrict__ out) {
  int i = blockIdx.x * 256 + threadIdx.x;
  if (i >= NB * NOUT) return;
  int b = i / NOUT;
  int r = i - b * NOUT;
  out[i] = (float)cnt2[b * D1 + idx_out[r]];
}

// ---------------------------------------------------------------------------
extern "C" void kernel_launch(void* const* d_in, const int* in_sizes, int n_in,
                              void* d_out, int out_size, void* d_ws, size_t ws_size,
                              hipStream_t stream) {
  const float* x      = (const float*)d_in[0];
  const float* w0     = (const float*)d_in[1];
  const float* t0     = (const float*)d_in[2];
  const float* w2     = (const float*)d_in[3];
  const float* t2     = (const float*)d_in[4];
  const int*   idx0   = (const int*)d_in[5];
  const int*   idx1   = (const int*)d_in[6];
  const int*   idx2   = (const int*)d_in[7];
  const int*   idx_out= (const int*)d_in[8];
  float* out = (float*)d_out;

  char* ws = (char*)d_ws;
  float*    w0T   = (float*)ws;    ws += (size_t)D0 * D0 * 4;   // 64 MB
  float*    w2T   = (float*)ws;    ws += (size_t)D1 * D1 * 4;   // 4 MB
  uint32_t* perm0 = (uint32_t*)ws; ws += (size_t)NB * D0 * 4;
  uint32_t* perm2 = (uint32_t*)ws; ws += (size_t)NB * D1 * 4;
  int*      N0    = (int*)ws;      ws += (size_t)NB * D0 * 4;
  int*      N1    = (int*)ws;      ws += (size_t)NB * D1 * 4;
  int*      k0    = (int*)ws;      ws += (size_t)NB * D0 * 4;
  int*      cnt2  = (int*)ws;      ws += (size_t)NB * D1 * 4;

  transpose_w0_k<<<dim3(D0 / 32, D0 / 32), dim3(32, 8), 0, stream>>>(w0, w0T);
  transpose_w2_k<<<dim3(D1 / 32, D1 / 32), dim3(32, 8), 0, stream>>>(w2, w2T);
  compute_N0_k<<<NB * D0 / 256, 256, 0, stream>>>(x, N0);
  prep_sort_k<D0><<<NB, 256, 0, stream>>>(N0, idx0, perm0);
  // grid x = o-tile (fastest varying) -> o-tiles round-robin over XCDs (%8),
  // bounding per-XCD w0T working set to ~8 MB across the 64-batch re-reads.
  lif_core_k<D0, D0><<<dim3(D0 / 256, NB), 256, 0, stream>>>(w0T, perm0, t0, k0);
  pool_encode_k<<<NB * D1 / 256, 256, 0, stream>>>(k0, idx1, N1);
  prep_sort_k<D1><<<NB, 256, 0, stream>>>(N1, idx2, perm2);
  lif_core_k<D1, D1><<<dim3(D1 / 256, NB), 256, 0, stream>>>(w2T, perm2, t2, cnt2);
  write_out_k<<<(NB * NOUT + 255) / 256, 256, 0, stream>>>(cnt2, idx_out, out);
}

// Round 2
// 579.017 us; speedup vs baseline: 3.0232x; 3.0232x over previous
//
#include <hip/hip_runtime.h>
#include <stdint.h>
#include <stddef.h>

#define D0 4096
#define D1 1024
#define NOUT 1000
#define NB 64

// ---------------------------------------------------------------------------
// Spike pattern for uniform spike coding, N in [0,32] -> 32-bit cycle mask.
// Matches jnp: spacing = 32.f/N (fp32), spike at c iff fmod(c, spacing) < 1.
// floor(c/spacing) < N is always true for 0<N<32 (margin >= N/32 >> fp eps).
// ---------------------------------------------------------------------------
__device__ __forceinline__ uint32_t spike_pattern(int N) {
  if (N <= 0) return 0u;
  if (N >= 32) return 0xFFFFFFFFu;
  float spacing = 32.0f / (float)N;
  uint32_t m = 0;
  for (int c = 0; c < 32; ++c) {
    if (fmodf((float)c, spacing) < 1.0f) m |= (1u << c);
  }
  return m;
}

// ---------------------------------------------------------------------------
// Transpose w0 (4096x4096) -> w0T[j][o]
// ---------------------------------------------------------------------------
__global__ void transpose_w0_k(const float* __restrict__ w, float* __restrict__ wt) {
  __shared__ float tile[32][33];
  int j0 = blockIdx.x * 32;
  int o0 = blockIdx.y * 32;
  int tx = threadIdx.x, ty = threadIdx.y; // 32 x 8
  for (int r = ty; r < 32; r += 8)
    tile[r][tx] = w[(size_t)(o0 + r) * D0 + j0 + tx];
  __syncthreads();
  for (int r = ty; r < 32; r += 8)
    wt[(size_t)(j0 + r) * D0 + o0 + tx] = tile[tx][r];
}

// Transpose w2 (1000x1024) -> w2T[j][o], o padded to 1024 with zeros.
__global__ void transpose_w2_k(const float* __restrict__ w, float* __restrict__ wt) {
  __shared__ float tile[32][33];
  int j0 = blockIdx.x * 32;
  int o0 = blockIdx.y * 32;
  int tx = threadIdx.x, ty = threadIdx.y;
  for (int r = ty; r < 32; r += 8) {
    int o = o0 + r;
    tile[r][tx] = (o < NOUT) ? w[(size_t)o * D1 + j0 + tx] : 0.0f;
  }
  __syncthreads();
  for (int r = ty; r < 32; r += 8)
    wt[(size_t)(j0 + r) * D1 + o0 + tx] = tile[tx][r];
}

// ---------------------------------------------------------------------------
// N0(b,d) = round_half_even(x * 32)   (matches jnp.round in fp32)
// ---------------------------------------------------------------------------
__global__ void compute_N0_k(const float* __restrict__ x, int* __restrict__ N0) {
  int i = blockIdx.x * 256 + threadIdx.x;
  N0[i] = (int)rintf(x[i] * 32.0f);
}

// ---------------------------------------------------------------------------
// Per-batch counting sort of D inputs by key = Nsrc[b][idx[j]] (33 keys).
// perm[b][pos] = j, sorted ascending by key; starts[b][k] = bucket k begin,
// k in [0,34). Order within a key is non-deterministic (atomics) — only
// perturbs fp64 bucket-sum rounding at ~1e-16, irrelevant vs threshold gaps.
// ---------------------------------------------------------------------------
template <int D>
__global__ void prep_sort_k(const int* __restrict__ Nsrc, const int* __restrict__ idx,
                            uint32_t* __restrict__ perm, int* __restrict__ starts) {
  __shared__ int keys[D];
  __shared__ int hist[33];
  __shared__ int base[34];
  __shared__ int cursor[33];
  int b = blockIdx.x;
  int tid = threadIdx.x;
  if (tid < 33) hist[tid] = 0;
  __syncthreads();
  for (int j = tid; j < D; j += 256) {
    int k = Nsrc[b * D + idx[j]];
    keys[j] = k;
    atomicAdd(&hist[k], 1);
  }
  __syncthreads();
  if (tid == 0) {
    int s = 0;
    for (int k = 0; k < 33; ++k) { base[k] = s; cursor[k] = s; s += hist[k]; }
    base[33] = s;
  }
  __syncthreads();
  if (tid < 34) starts[b * 34 + tid] = base[tid];
  for (int j = tid; j < D; j += 256) {
    int k = keys[j];
    int pos = atomicAdd(&cursor[k], 1);
    perm[b * D + pos] = (uint32_t)j;
  }
}

// ---------------------------------------------------------------------------
// LIF core via bucket decomposition, fp64-exact, branch-free segment scan.
// Thread = one output neuron o for batch b. For each key k, sum its segment
// of w0T rows with 8-wide unrolled independent loads (perm/starts are
// block-uniform -> scalar loads), then scatter the fp64 bucket sum into
// contrib[t] per the key's spike pattern. Finally run the 32-step membrane
// scan (threshold-subtract reset) and emit the spike count.
// o_tile = blockIdx.x + gridDim.x * blockIdx.z so that (with XCD = linear%8)
// each XCD streams one 4 MB o-slice of wt at a time -> L2-resident.
// ---------------------------------------------------------------------------
template <int D, int OSTRIDE>
__launch_bounds__(256, 4)
__global__ void lif_core_k(const float* __restrict__ wt, const uint32_t* __restrict__ perm,
                           const int* __restrict__ starts, const float* __restrict__ thr_p,
                           int* __restrict__ cnt_out) {
  __shared__ uint32_t pat[33];
  int tid = threadIdx.x;
  int o_tile = blockIdx.x + gridDim.x * blockIdx.z;
  int o = o_tile * 256 + tid;
  int b = blockIdx.y;
  if (tid < 33) pat[tid] = spike_pattern(tid);
  __syncthreads();

  double contrib[32];
#pragma unroll
  for (int t = 0; t < 32; ++t) contrib[t] = 0.0;

  const uint32_t* permb = perm + (size_t)b * D;
  const int* st = starts + b * 34;

  for (int k = 1; k <= 32; ++k) {   // k=0: pattern is empty, skip its segment
    int s = st[k], e = st[k + 1];
    if (s == e) continue;           // uniform branch
    double a0 = 0.0, a1 = 0.0, a2 = 0.0, a3 = 0.0;
    int i = s;
    for (; i + 8 <= e; i += 8) {
      uint32_t j0 = permb[i + 0], j1 = permb[i + 1], j2 = permb[i + 2], j3 = permb[i + 3];
      uint32_t j4 = permb[i + 4], j5 = permb[i + 5], j6 = permb[i + 6], j7 = permb[i + 7];
      float f0 = wt[(size_t)j0 * OSTRIDE + o];
      float f1 = wt[(size_t)j1 * OSTRIDE + o];
      float f2 = wt[(size_t)j2 * OSTRIDE + o];
      float f3 = wt[(size_t)j3 * OSTRIDE + o];
      float f4 = wt[(size_t)j4 * OSTRIDE + o];
      float f5 = wt[(size_t)j5 * OSTRIDE + o];
      float f6 = wt[(size_t)j6 * OSTRIDE + o];
      float f7 = wt[(size_t)j7 * OSTRIDE + o];
      a0 += (double)f0; a1 += (double)f1; a2 += (double)f2; a3 += (double)f3;
      a0 += (double)f4; a1 += (double)f5; a2 += (double)f6; a3 += (double)f7;
    }
    for (; i < e; ++i)
      a0 += (double)wt[(size_t)permb[i] * OSTRIDE + o];
    double acc = (a0 + a1) + (a2 + a3);
    uint32_t m = pat[k];
#pragma unroll
    for (int t = 0; t < 32; ++t)
      contrib[t] += ((m >> t) & 1u) ? acc : 0.0;
  }

  double th = (double)thr_p[0];
  double memb = 0.0;
  int cnt = 0;
#pragma unroll
  for (int t = 0; t < 32; ++t) {
    memb += contrib[t];
    if (memb > th) { memb -= th; ++cnt; }  // strict: threshold < memb
  }
  cnt_out[(size_t)b * OSTRIDE + o] = cnt;
}

// ---------------------------------------------------------------------------
// avg_pool2d on exact spike counts + re-encode: N1 = round_half_even(count4/4)
// rates are exact multiples of 1/128; clip is a no-op (count4 <= 128).
// ---------------------------------------------------------------------------
__global__ void pool_encode_k(const int* __restrict__ k0, const int* __restrict__ idx1,
                              int* __restrict__ N1) {
  int i = blockIdx.x * 256 + threadIdx.x;  // 64*1024
  int b = i >> 10;
  int q2 = i & 1023;
  int c = q2 >> 4;
  int h2 = (q2 >> 2) & 3;
  int w2 = q2 & 3;
  int cnt = 0;
#pragma unroll
  for (int dh = 0; dh < 2; ++dh)
#pragma unroll
    for (int dw = 0; dw < 2; ++dw) {
      int q = c * 64 + (2 * h2 + dh) * 8 + (2 * w2 + dw);
      cnt += k0[b * D0 + idx1[q]];
    }
  N1[i] = (int)rintf((float)cnt * 0.25f);
}

__global__ void write_out_k(const int* __restrict__ cnt2, const int* __restrict__ idx_out,
                            float* __restrict__ out) {
  int i = blockIdx.x * 256 + threadIdx.x;
  if (i >= NB * NOUT) return;
  int b = i / NOUT;
  int r = i - b * NOUT;
  out[i] = (float)cnt2[b * D1 + idx_out[r]];
}

// ---------------------------------------------------------------------------
extern "C" void kernel_launch(void* const* d_in, const int* in_sizes, int n_in,
                              void* d_out, int out_size, void* d_ws, size_t ws_size,
                              hipStream_t stream) {
  const float* x      = (const float*)d_in[0];
  const float* w0     = (const float*)d_in[1];
  const float* t0     = (const float*)d_in[2];
  const float* w2     = (const float*)d_in[3];
  const float* t2     = (const float*)d_in[4];
  const int*   idx0   = (const int*)d_in[5];
  const int*   idx1   = (const int*)d_in[6];
  const int*   idx2   = (const int*)d_in[7];
  const int*   idx_out= (const int*)d_in[8];
  float* out = (float*)d_out;

  char* ws = (char*)d_ws;
  float*    w0T    = (float*)ws;    ws += (size_t)D0 * D0 * 4;   // 64 MB
  float*    w2T    = (float*)ws;    ws += (size_t)D1 * D1 * 4;   // 4 MB
  uint32_t* perm0  = (uint32_t*)ws; ws += (size_t)NB * D0 * 4;
  uint32_t* perm2  = (uint32_t*)ws; ws += (size_t)NB * D1 * 4;
  int*      N0     = (int*)ws;      ws += (size_t)NB * D0 * 4;
  int*      N1     = (int*)ws;      ws += (size_t)NB * D1 * 4;
  int*      k0     = (int*)ws;      ws += (size_t)NB * D0 * 4;
  int*      cnt2   = (int*)ws;      ws += (size_t)NB * D1 * 4;
  int*      starts0= (int*)ws;      ws += (size_t)NB * 34 * 4;
  int*      starts2= (int*)ws;      ws += (size_t)NB * 34 * 4;

  transpose_w0_k<<<dim3(D0 / 32, D0 / 32), dim3(32, 8), 0, stream>>>(w0, w0T);
  transpose_w2_k<<<dim3(D1 / 32, D1 / 32), dim3(32, 8), 0, stream>>>(w2, w2T);
  compute_N0_k<<<NB * D0 / 256, 256, 0, stream>>>(x, N0);
  prep_sort_k<D0><<<NB, 256, 0, stream>>>(N0, idx0, perm0, starts0);
  // grid (8, NB, 2): o_tile = x + 8z -> each XCD (linear%8 == x) streams one
  // 4 MB w0T o-slice across all 64 batches before moving to its second slice.
  lif_core_k<D0, D0><<<dim3(8, NB, 2), 256, 0, stream>>>(w0T, perm0, starts0, t0, k0);
  pool_encode_k<<<NB * D1 / 256, 256, 0, stream>>>(k0, idx1, N1);
  prep_sort_k<D1><<<NB, 256, 0, stream>>>(N1, idx2, perm2, starts2);
  lif_core_k<D1, D1><<<dim3(D1 / 256, NB, 1), 256, 0, stream>>>(w2T, perm2, starts2, t2, cnt2);
  write_out_k<<<(NB * NOUT + 255) / 256, 256, 0, stream>>>(cnt2, idx_out, out);
}